// Round 1
// baseline (414.264 us; speedup 1.0000x reference)
//
#include <hip/hip_runtime.h>

typedef __bf16 bf16_t;
typedef __attribute__((ext_vector_type(8))) __bf16 bf16x8;
typedef __attribute__((ext_vector_type(4))) __bf16 bf16x4;
typedef __attribute__((ext_vector_type(4))) float f32x4;

#define B_  4
#define L_  2048
#define D_  1024
#define M_  (B_*L_)

__device__ __forceinline__ void gload_lds16(const void* g, void* l) {
  __builtin_amdgcn_global_load_lds(
      (__attribute__((address_space(1))) void*)(g),
      (__attribute__((address_space(3))) void*)(l), 16, 0, 0);
}

// C[M][N] = A[M][K] * Bt[N][K]^T, optional +bias[col], *scale.
// 128x128 tile, BK=64, 256 threads (4 waves as 2x2, each 64x64 = 4x4 frags of 16x16x32).
template<bool OUT_BF16, bool CAUSAL, bool VARK>
__global__ __launch_bounds__(256)
void gemm_abt(const bf16_t* __restrict__ A, int lda,
              const bf16_t* __restrict__ Bt, int ldb,
              void* __restrict__ Cv, int ldc,
              const float* __restrict__ bias, float scale, int K)
{
  if (CAUSAL && blockIdx.x > blockIdx.y) return;   // fully above diagonal
  const int tid  = threadIdx.x;
  const int wid  = tid >> 6, lane = tid & 63;
  const int wm   = wid >> 1, wn = wid & 1;
  const int r0   = blockIdx.y * 128, c0 = blockIdx.x * 128;
  const int kend = VARK ? min(K, r0 + 128) : K;

  __shared__ __align__(16) bf16_t As[128][64];
  __shared__ __align__(16) bf16_t Bs[128][64];

  f32x4 acc[4][4] = {};

  const int srow = tid >> 3;          // 0..31
  const int scol = (tid & 7) * 8;     // 0..56 step 8

  for (int k0 = 0; k0 < kend; k0 += 64) {
    #pragma unroll
    for (int i = 0; i < 4; ++i) {
      gload_lds16(A  + (size_t)(r0 + i*32 + srow) * lda + (k0 + scol),
                  &As[0][0] + i*2048 + wid*512);
      gload_lds16(Bt + (size_t)(c0 + i*32 + srow) * ldb + (k0 + scol),
                  &Bs[0][0] + i*2048 + wid*512);
    }
    __syncthreads();
    #pragma unroll
    for (int ks = 0; ks < 2; ++ks) {
      bf16x8 af[4], bfr[4];
      #pragma unroll
      for (int i = 0; i < 4; ++i)
        af[i]  = *(const bf16x8*)(&As[wm*64 + i*16 + (lane & 15)][ks*32 + (lane >> 4)*8]);
      #pragma unroll
      for (int i = 0; i < 4; ++i)
        bfr[i] = *(const bf16x8*)(&Bs[wn*64 + i*16 + (lane & 15)][ks*32 + (lane >> 4)*8]);
      #pragma unroll
      for (int mi = 0; mi < 4; ++mi)
        #pragma unroll
        for (int ni = 0; ni < 4; ++ni)
          acc[mi][ni] = __builtin_amdgcn_mfma_f32_16x16x32_bf16(af[mi], bfr[ni], acc[mi][ni], 0, 0, 0);
    }
    __syncthreads();
  }

  const int ci = lane & 15, ri = (lane >> 4) * 4;
  #pragma unroll
  for (int mi = 0; mi < 4; ++mi) {
    #pragma unroll
    for (int ni = 0; ni < 4; ++ni) {
      const int c = c0 + wn*64 + ni*16 + ci;
      const float bb = bias ? bias[c] : 0.0f;
      #pragma unroll
      for (int j = 0; j < 4; ++j) {
        const int r = r0 + wm*64 + mi*16 + ri + j;
        const float v = (acc[mi][ni][j] + bb) * scale;
        if (OUT_BF16) ((bf16_t*)Cv)[(size_t)r * ldc + c] = (bf16_t)v;
        else          ((float*)Cv)[(size_t)r * ldc + c] = v;
      }
    }
  }
}

__device__ __forceinline__ float blk_red_max(float v, float* red, int lane, int wid) {
  #pragma unroll
  for (int o = 32; o; o >>= 1) v = fmaxf(v, __shfl_down(v, o));
  __syncthreads();
  if (lane == 0) red[wid] = v;
  __syncthreads();
  return fmaxf(fmaxf(red[0], red[1]), fmaxf(red[2], red[3]));
}
__device__ __forceinline__ float blk_red_sum(float v, float* red, int lane, int wid) {
  #pragma unroll
  for (int o = 32; o; o >>= 1) v += __shfl_down(v, o);
  __syncthreads();
  if (lane == 0) red[wid] = v;
  __syncthreads();
  return red[0] + red[1] + red[2] + red[3];
}

// one block per row r; softmax over S[r][0..r], write bf16 P, zero-fill to 128-aligned end
__global__ __launch_bounds__(256)
void softmax_causal(const float* __restrict__ S, bf16_t* __restrict__ P) {
  const int r = blockIdx.x;
  const int n = r + 1;
  const int kend = min(((n + 127) >> 7) << 7, L_);
  const float* row = S + (size_t)r * L_;
  bf16_t* prow = P + (size_t)r * L_;
  const int tid = threadIdx.x, lane = tid & 63, wid = tid >> 6;
  __shared__ float red[4];

  float mx = -3.402823466e38f;
  #pragma unroll
  for (int i = 0; i < 8; ++i) {
    const int c = tid + i*256;
    if (c < n) mx = fmaxf(mx, row[c]);
  }
  mx = blk_red_max(mx, red, lane, wid);

  float e[8]; float sum = 0.f;
  #pragma unroll
  for (int i = 0; i < 8; ++i) {
    const int c = tid + i*256;
    const float v = (c < n) ? __expf(row[c] - mx) : 0.f;
    e[i] = v; sum += v;
  }
  sum = blk_red_sum(sum, red, lane, wid);
  const float inv = 1.0f / sum;
  #pragma unroll
  for (int i = 0; i < 8; ++i) {
    const int c = tid + i*256;
    if (c < kend) prow[c] = (bf16_t)(e[i] * inv);   // e==0 in [n,kend) -> zeros
  }
}

__global__ void cvt_f32_bf16(const float* __restrict__ in, bf16_t* __restrict__ out, int n4) {
  const int stride = gridDim.x * blockDim.x;
  for (int i = blockIdx.x * blockDim.x + threadIdx.x; i < n4; i += stride) {
    const float4 v = ((const float4*)in)[i];
    bf16x4 o = { (bf16_t)v.x, (bf16_t)v.y, (bf16_t)v.z, (bf16_t)v.w };
    ((bf16x4*)out)[i] = o;
  }
}

// oT[z][n][k] = w_z[k][n], fp32 -> bf16, 1024x1024 each
__global__ void transpose_w3(const float* __restrict__ w0, const float* __restrict__ w1,
                             const float* __restrict__ w2, bf16_t* __restrict__ oT) {
  const float* w = blockIdx.z == 0 ? w0 : (blockIdx.z == 1 ? w1 : w2);
  bf16_t* o = oT + (size_t)blockIdx.z * D_ * D_;
  __shared__ float t[32][33];
  const int tx = threadIdx.x, ty = threadIdx.y;
  const int x  = blockIdx.x*32 + tx;
  const int y0 = blockIdx.y*32;
  #pragma unroll
  for (int j = 0; j < 4; ++j)
    t[ty + j*8][tx] = w[(size_t)(y0 + ty + j*8) * D_ + x];
  __syncthreads();
  const int x2 = y0 + tx;
  const int y2 = blockIdx.x*32;
  #pragma unroll
  for (int j = 0; j < 4; ++j)
    o[(size_t)(y2 + ty + j*8) * D_ + x2] = (bf16_t)t[tx][ty + j*8];
}

// out[C][R] = in[R][C], bf16
__global__ void transpose_bf16(const bf16_t* __restrict__ in, bf16_t* __restrict__ out,
                               int R, int C) {
  __shared__ bf16_t t[32][34];
  const int tx = threadIdx.x, ty = threadIdx.y;
  const int x  = blockIdx.x*32 + tx;
  const int y0 = blockIdx.y*32;
  #pragma unroll
  for (int j = 0; j < 4; ++j)
    t[ty + j*8][tx] = in[(size_t)(y0 + ty + j*8) * C + x];
  __syncthreads();
  const int x2 = y0 + tx;
  const int y2 = blockIdx.x*32;
  #pragma unroll
  for (int j = 0; j < 4; ++j)
    out[(size_t)(y2 + ty + j*8) * R + x2] = t[tx][ty + j*8];
}

extern "C" void kernel_launch(void* const* d_in, const int* in_sizes, int n_in,
                              void* d_out, int out_size, void* d_ws, size_t ws_size,
                              hipStream_t stream) {
  const float* x  = (const float*)d_in[0];
  // d_in[1] = causal mask, structurally known -> ignored
  const float* wq = (const float*)d_in[2];
  const float* bq = (const float*)d_in[3];
  const float* wk = (const float*)d_in[4];
  const float* bk = (const float*)d_in[5];
  const float* wv = (const float*)d_in[6];
  const float* bv = (const float*)d_in[7];
  float* out = (float*)d_out;

  // workspace layout (bf16 elems unless noted); S aliases xb, P aliases vb.
  bf16_t* xb  = (bf16_t*)d_ws;                  // [8192][1024]   16 MB
  bf16_t* wT  = xb  + (size_t)M_ * D_;          // [3][1024][1024] 6 MB (W^T)
  bf16_t* qb  = wT  + (size_t)3 * D_ * D_;      // [8192][1024]   16 MB (pre-scaled 1/32)
  bf16_t* kb  = qb  + (size_t)M_ * D_;          // [8192][1024]   16 MB
  bf16_t* vb  = kb  + (size_t)M_ * D_;          // [8192][1024]   16 MB
  bf16_t* vbT = vb  + (size_t)M_ * D_;          // [1024][8192]   16 MB (V^T)
  float*  S   = (float*)xb;                     // [2048][2048] f32, per-batch reuse
  bf16_t* P   = vb;                             // [2048][2048] bf16, per-batch reuse

  cvt_f32_bf16<<<1024, 256, 0, stream>>>(x, xb, M_ * D_ / 4);
  transpose_w3<<<dim3(32,32,3), dim3(32,8), 0, stream>>>(wq, wk, wv, wT);

  dim3 gp(D_/128, M_/128);
  gemm_abt<true,false,false><<<gp, 256, 0, stream>>>(xb, D_, wT,             D_, qb, D_, bq, 0.03125f, D_);
  gemm_abt<true,false,false><<<gp, 256, 0, stream>>>(xb, D_, wT +   D_*D_,   D_, kb, D_, bk, 1.0f,    D_);
  gemm_abt<true,false,false><<<gp, 256, 0, stream>>>(xb, D_, wT + 2*D_*D_,   D_, vb, D_, bv, 1.0f,    D_);

  transpose_bf16<<<dim3(D_/32, M_/32), dim3(32,8), 0, stream>>>(vb, vbT, M_, D_);

  for (int b = 0; b < B_; ++b) {
    const bf16_t* Qb = qb  + (size_t)b * L_ * D_;
    const bf16_t* Kb = kb  + (size_t)b * L_ * D_;
    const bf16_t* Vt = vbT + (size_t)b * L_;     // ldb = M_ (8192)
    float*        Ob = out + (size_t)b * L_ * D_;
    gemm_abt<false,true ,false><<<dim3(L_/128, L_/128), 256, 0, stream>>>(Qb, D_, Kb, D_, S,  L_, nullptr, 1.0f, D_);
    softmax_causal<<<L_, 256, 0, stream>>>(S, P);
    gemm_abt<false,false,true ><<<dim3(D_/128, L_/128), 256, 0, stream>>>(P,  L_, Vt, M_, Ob, D_, nullptr, 1.0f, L_);
  }
}

// Round 2
// 233.731 us; speedup vs baseline: 1.7724x; 1.7724x over previous
//
#include <hip/hip_runtime.h>

typedef __bf16 bf16_t;
typedef __attribute__((ext_vector_type(8))) __bf16 bf16x8;
typedef __attribute__((ext_vector_type(4))) __bf16 bf16x4;
typedef __attribute__((ext_vector_type(4))) float f32x4;

#define B_  4
#define L_  2048
#define D_  1024
#define M_  (B_*L_)

__device__ __forceinline__ void gload_lds16(const void* g, void* l) {
  __builtin_amdgcn_global_load_lds(
      (__attribute__((address_space(1))) void*)(g),
      (__attribute__((address_space(3))) void*)(l), 16, 0, 0);
}

// C[M][N] = A[M][K] * Bt[N][K]^T, optional +bias[col], *scale.
// 128x128 tile, BK=64, 256 threads (4 waves as 2x2, each 64x64 = 4x4 frags of 16x16x32).
// blockIdx.z selects a batch/projection slab via strides sA/sB/sC.
template<bool OUT_BF16, bool CAUSAL, bool VARK, bool PROJ>
__global__ __launch_bounds__(256)
void gemm_abt(const bf16_t* __restrict__ A, int lda, long sA,
              const bf16_t* __restrict__ Bt, int ldb, long sB,
              void* __restrict__ Cv, int ldc, long sC,
              const float* __restrict__ b0, const float* __restrict__ b1,
              const float* __restrict__ b2, float scale, int K)
{
  if (CAUSAL && blockIdx.x > blockIdx.y) return;   // fully above diagonal
  const int z = blockIdx.z;
  A  += (size_t)z * sA;
  Bt += (size_t)z * sB;
  const float* bias;
  if (PROJ) { bias = (z == 0) ? b0 : (z == 1) ? b1 : b2; scale = (z == 0) ? 0.03125f : 1.0f; }
  else        bias = b0;   // may be null

  const int tid  = threadIdx.x;
  const int wid  = tid >> 6, lane = tid & 63;
  const int wm   = wid >> 1, wn = wid & 1;
  const int r0   = blockIdx.y * 128, c0 = blockIdx.x * 128;
  const int kend = VARK ? min(K, r0 + 128) : K;

  __shared__ __align__(16) bf16_t As[128][64];
  __shared__ __align__(16) bf16_t Bs[128][64];

  f32x4 acc[4][4] = {};

  const int srow = tid >> 3;          // 0..31
  const int scol = (tid & 7) * 8;     // 0..56 step 8

  for (int k0 = 0; k0 < kend; k0 += 64) {
    #pragma unroll
    for (int i = 0; i < 4; ++i) {
      gload_lds16(A  + (size_t)(r0 + i*32 + srow) * lda + (k0 + scol),
                  &As[0][0] + i*2048 + wid*512);
      gload_lds16(Bt + (size_t)(c0 + i*32 + srow) * ldb + (k0 + scol),
                  &Bs[0][0] + i*2048 + wid*512);
    }
    __syncthreads();
    #pragma unroll
    for (int ks = 0; ks < 2; ++ks) {
      bf16x8 af[4], bfr[4];
      #pragma unroll
      for (int i = 0; i < 4; ++i)
        af[i]  = *(const bf16x8*)(&As[wm*64 + i*16 + (lane & 15)][ks*32 + (lane >> 4)*8]);
      #pragma unroll
      for (int i = 0; i < 4; ++i)
        bfr[i] = *(const bf16x8*)(&Bs[wn*64 + i*16 + (lane & 15)][ks*32 + (lane >> 4)*8]);
      #pragma unroll
      for (int mi = 0; mi < 4; ++mi)
        #pragma unroll
        for (int ni = 0; ni < 4; ++ni)
          acc[mi][ni] = __builtin_amdgcn_mfma_f32_16x16x32_bf16(af[mi], bfr[ni], acc[mi][ni], 0, 0, 0);
    }
    __syncthreads();
  }

  const int ci = lane & 15, ri = (lane >> 4) * 4;
  #pragma unroll
  for (int mi = 0; mi < 4; ++mi) {
    #pragma unroll
    for (int ni = 0; ni < 4; ++ni) {
      const int c = c0 + wn*64 + ni*16 + ci;
      const float bb = bias ? bias[c] : 0.0f;
      #pragma unroll
      for (int j = 0; j < 4; ++j) {
        const int r = r0 + wm*64 + mi*16 + ri + j;
        const float v = (acc[mi][ni][j] + bb) * scale;
        if (OUT_BF16) ((bf16_t*)Cv + (size_t)z * sC)[(size_t)r * ldc + c] = (bf16_t)v;
        else          ((float*)Cv  + (size_t)z * sC)[(size_t)r * ldc + c] = v;
      }
    }
  }
}

__device__ __forceinline__ float blk_red_max(float v, float* red, int lane, int wid) {
  #pragma unroll
  for (int o = 32; o; o >>= 1) v = fmaxf(v, __shfl_down(v, o));
  __syncthreads();
  if (lane == 0) red[wid] = v;
  __syncthreads();
  return fmaxf(fmaxf(red[0], red[1]), fmaxf(red[2], red[3]));
}
__device__ __forceinline__ float blk_red_sum(float v, float* red, int lane, int wid) {
  #pragma unroll
  for (int o = 32; o; o >>= 1) v += __shfl_down(v, o);
  __syncthreads();
  if (lane == 0) red[wid] = v;
  __syncthreads();
  return red[0] + red[1] + red[2] + red[3];
}

// block (x=row r, y=batch); softmax over S[r][0..r], write bf16 P, zero-fill to 128-aligned end
__global__ __launch_bounds__(256)
void softmax_causal(const float* __restrict__ S, bf16_t* __restrict__ P) {
  const int r = blockIdx.x;
  const int n = r + 1;
  const int kend = min(((n + 127) >> 7) << 7, L_);
  const float* row = S + (size_t)blockIdx.y * L_ * L_ + (size_t)r * L_;
  bf16_t* prow = P + (size_t)blockIdx.y * L_ * L_ + (size_t)r * L_;
  const int tid = threadIdx.x, lane = tid & 63, wid = tid >> 6;
  __shared__ float red[4];

  float mx = -3.402823466e38f;
  #pragma unroll
  for (int i = 0; i < 8; ++i) {
    const int c = tid + i*256;
    if (c < n) mx = fmaxf(mx, row[c]);
  }
  mx = blk_red_max(mx, red, lane, wid);

  float e[8]; float sum = 0.f;
  #pragma unroll
  for (int i = 0; i < 8; ++i) {
    const int c = tid + i*256;
    const float v = (c < n) ? __expf(row[c] - mx) : 0.f;
    e[i] = v; sum += v;
  }
  sum = blk_red_sum(sum, red, lane, wid);
  const float inv = 1.0f / sum;
  #pragma unroll
  for (int i = 0; i < 8; ++i) {
    const int c = tid + i*256;
    if (c < kend) prow[c] = (bf16_t)(e[i] * inv);   // e==0 in [n,kend) -> zeros
  }
}

__global__ void cvt_f32_bf16(const float* __restrict__ in, bf16_t* __restrict__ out, int n4) {
  const int stride = gridDim.x * blockDim.x;
  for (int i = blockIdx.x * blockDim.x + threadIdx.x; i < n4; i += stride) {
    const float4 v = ((const float4*)in)[i];
    bf16x4 o = { (bf16_t)v.x, (bf16_t)v.y, (bf16_t)v.z, (bf16_t)v.w };
    ((bf16x4*)out)[i] = o;
  }
}

// oT[z][n][k] = w_z[k][n], fp32 -> bf16, 1024x1024 each
__global__ void transpose_w3(const float* __restrict__ w0, const float* __restrict__ w1,
                             const float* __restrict__ w2, bf16_t* __restrict__ oT) {
  const float* w = blockIdx.z == 0 ? w0 : (blockIdx.z == 1 ? w1 : w2);
  bf16_t* o = oT + (size_t)blockIdx.z * D_ * D_;
  __shared__ float t[32][33];
  const int tx = threadIdx.x, ty = threadIdx.y;
  const int x  = blockIdx.x*32 + tx;
  const int y0 = blockIdx.y*32;
  #pragma unroll
  for (int j = 0; j < 4; ++j)
    t[ty + j*8][tx] = w[(size_t)(y0 + ty + j*8) * D_ + x];
  __syncthreads();
  const int x2 = y0 + tx;
  const int y2 = blockIdx.x*32;
  #pragma unroll
  for (int j = 0; j < 4; ++j)
    o[(size_t)(y2 + ty + j*8) * D_ + x2] = (bf16_t)t[tx][ty + j*8];
}

// out[C][R] = in[R][C], bf16
__global__ void transpose_bf16(const bf16_t* __restrict__ in, bf16_t* __restrict__ out,
                               int R, int C) {
  __shared__ bf16_t t[32][34];
  const int tx = threadIdx.x, ty = threadIdx.y;
  const int x  = blockIdx.x*32 + tx;
  const int y0 = blockIdx.y*32;
  #pragma unroll
  for (int j = 0; j < 4; ++j)
    t[ty + j*8][tx] = in[(size_t)(y0 + ty + j*8) * C + x];
  __syncthreads();
  const int x2 = y0 + tx;
  const int y2 = blockIdx.x*32;
  #pragma unroll
  for (int j = 0; j < 4; ++j)
    out[(size_t)(y2 + ty + j*8) * R + x2] = t[tx][ty + j*8];
}

extern "C" void kernel_launch(void* const* d_in, const int* in_sizes, int n_in,
                              void* d_out, int out_size, void* d_ws, size_t ws_size,
                              hipStream_t stream) {
  const float* x  = (const float*)d_in[0];
  // d_in[1] = causal mask, structurally known -> ignored
  const float* wq = (const float*)d_in[2];
  const float* bq = (const float*)d_in[3];
  const float* wk = (const float*)d_in[4];
  const float* bk = (const float*)d_in[5];
  const float* wv = (const float*)d_in[6];
  const float* bv = (const float*)d_in[7];
  float* out = (float*)d_out;

  // workspace layout (bf16 elems unless noted)
  bf16_t* xb  = (bf16_t*)d_ws;                  // [8192][1024]   16 MB
  bf16_t* wT  = xb  + (size_t)M_ * D_;          // [3][1024][1024] 6 MB (W^T)
  bf16_t* qb  = wT  + (size_t)3 * D_ * D_;      // [8192][1024]   16 MB (pre-scaled 1/32)
  bf16_t* kb  = qb  + (size_t)M_ * D_;          // [8192][1024]   16 MB
  bf16_t* vb  = kb  + (size_t)M_ * D_;          // [8192][1024]   16 MB
  bf16_t* vbT = vb  + (size_t)M_ * D_;          // [1024][8192]   16 MB (V^T)
  float*  Sfull = (float*)(vbT + (size_t)M_ * D_); // [4][2048][2048] f32, 64 MB
  bf16_t* Pfull = qb;                            // [4][2048][2048] bf16, 32 MB (aliases dead qb+kb)

  const size_t need_batched =
      (size_t)M_ * D_ * 2 * 5 + (size_t)3 * D_ * D_ * 2 + (size_t)B_ * L_ * L_ * 4;

  cvt_f32_bf16<<<1024, 256, 0, stream>>>(x, xb, M_ * D_ / 4);
  transpose_w3<<<dim3(32,32,3), dim3(32,8), 0, stream>>>(wq, wk, wv, wT);

  // fused 3-way projection: z picks {q,k,v}
  gemm_abt<true,false,false,true><<<dim3(D_/128, M_/128, 3), 256, 0, stream>>>(
      xb, D_, 0, wT, D_, (long)D_*D_, qb, D_, (long)M_*D_, bq, bk, bv, 1.0f, D_);

  transpose_bf16<<<dim3(D_/32, M_/32), dim3(32,8), 0, stream>>>(vb, vbT, M_, D_);

  if (ws_size >= need_batched) {
    // QK^T for all batches
    gemm_abt<false,true,false,false><<<dim3(L_/128, L_/128, B_), 256, 0, stream>>>(
        qb, D_, (long)L_*D_, kb, D_, (long)L_*D_, Sfull, L_, (long)L_*L_,
        nullptr, nullptr, nullptr, 1.0f, D_);
    // softmax for all batches (writes Pfull over dead qb+kb)
    softmax_causal<<<dim3(L_, B_), 256, 0, stream>>>(Sfull, Pfull);
    // PV for all batches
    gemm_abt<false,false,true,false><<<dim3(D_/128, L_/128, B_), 256, 0, stream>>>(
        Pfull, L_, (long)L_*L_, vbT, M_, (long)L_, out, D_, (long)L_*D_,
        nullptr, nullptr, nullptr, 1.0f, L_);
  } else {
    // fallback: per-batch, S aliases xb (dead), P aliases vb (vbT is used, vb is dead)
    float*  S = (float*)xb;
    bf16_t* P = vb;
    for (int b = 0; b < B_; ++b) {
      const bf16_t* Qb = qb  + (size_t)b * L_ * D_;
      const bf16_t* Kb = kb  + (size_t)b * L_ * D_;
      const bf16_t* Vt = vbT + (size_t)b * L_;
      float*        Ob = out + (size_t)b * L_ * D_;
      gemm_abt<false,true ,false,false><<<dim3(L_/128, L_/128), 256, 0, stream>>>(
          Qb, D_, 0, Kb, D_, 0, S, L_, 0, nullptr, nullptr, nullptr, 1.0f, D_);
      softmax_causal<<<dim3(L_, 1), 256, 0, stream>>>(S, P);
      gemm_abt<false,false,true ,false><<<dim3(D_/128, L_/128), 256, 0, stream>>>(
          P, L_, 0, Vt, M_, 0, Ob, D_, 0, nullptr, nullptr, nullptr, 1.0f, L_);
    }
  }
}

// Round 3
// 233.137 us; speedup vs baseline: 1.7769x; 1.0025x over previous
//
#include <hip/hip_runtime.h>

typedef __bf16 bf16_t;
typedef __attribute__((ext_vector_type(8))) __bf16 bf16x8;
typedef __attribute__((ext_vector_type(4))) __bf16 bf16x4;
typedef __attribute__((ext_vector_type(4))) float f32x4;

#define B_  4
#define L_  2048
#define D_  1024
#define M_  (B_*L_)
#define N3_ (3*D_)

__device__ __forceinline__ void gload_lds16(const void* g, void* l) {
  __builtin_amdgcn_global_load_lds(
      (__attribute__((address_space(1))) void*)(g),
      (__attribute__((address_space(3))) void*)(l), 16, 0, 0);
}

// C[M][N] = A[M][K] * Bt[N][K]^T (+bias)*scale.
// 128x128 tile, BK=64, 256 threads (4 waves as 2x2, each 64x64 = 4x4 frags of 16x16x32).
// blockIdx.z selects a batch slab via strides sA/sB/sC.
// XCD-aware bijective swizzle on (x,y); requires gridDim.x*gridDim.y % 8 == 0.
template<bool OUT_BF16, bool CAUSAL, bool VARK, bool PROJ>
__global__ __launch_bounds__(256)
void gemm_abt(const bf16_t* __restrict__ A, int lda, long sA,
              const bf16_t* __restrict__ Bt, int ldb, long sB,
              void* __restrict__ Cv, int ldc, long sC,
              const float* __restrict__ b0, const float* __restrict__ b1,
              const float* __restrict__ b2, float scale, int K)
{
  const int gx = gridDim.x;
  const int nwg = gx * gridDim.y;
  const int orig = blockIdx.y * gx + blockIdx.x;
  const int swz = (orig & 7) * (nwg >> 3) + (orig >> 3);   // XCD chunking (T1)
  const int bx = swz % gx, by = swz / gx;
  if (CAUSAL && bx > by) return;   // fully above diagonal

  const int z = blockIdx.z;
  A  += (size_t)z * sA;
  Bt += (size_t)z * sB;

  const int tid  = threadIdx.x;
  const int wid  = tid >> 6, lane = tid & 63;
  const int wm   = wid >> 1, wn = wid & 1;
  const int r0   = by * 128, c0 = bx * 128;
  const int kend = VARK ? min(K, r0 + 128) : K;

  __shared__ __align__(16) bf16_t As[128][64];
  __shared__ __align__(16) bf16_t Bs[128][64];

  f32x4 acc[4][4] = {};

  const int srow = tid >> 3;          // 0..31
  const int scol = (tid & 7) * 8;     // 0..56 step 8

  for (int k0 = 0; k0 < kend; k0 += 64) {
    #pragma unroll
    for (int i = 0; i < 4; ++i) {
      gload_lds16(A  + (size_t)(r0 + i*32 + srow) * lda + (k0 + scol),
                  &As[0][0] + i*2048 + wid*512);
      gload_lds16(Bt + (size_t)(c0 + i*32 + srow) * ldb + (k0 + scol),
                  &Bs[0][0] + i*2048 + wid*512);
    }
    __syncthreads();
    #pragma unroll
    for (int ks = 0; ks < 2; ++ks) {
      bf16x8 af[4], bfr[4];
      #pragma unroll
      for (int i = 0; i < 4; ++i)
        af[i]  = *(const bf16x8*)(&As[wm*64 + i*16 + (lane & 15)][ks*32 + (lane >> 4)*8]);
      #pragma unroll
      for (int i = 0; i < 4; ++i)
        bfr[i] = *(const bf16x8*)(&Bs[wn*64 + i*16 + (lane & 15)][ks*32 + (lane >> 4)*8]);
      #pragma unroll
      for (int mi = 0; mi < 4; ++mi)
        #pragma unroll
        for (int ni = 0; ni < 4; ++ni)
          acc[mi][ni] = __builtin_amdgcn_mfma_f32_16x16x32_bf16(af[mi], bfr[ni], acc[mi][ni], 0, 0, 0);
    }
    __syncthreads();
  }

  const int ci = lane & 15, ri = (lane >> 4) * 4;
  #pragma unroll
  for (int mi = 0; mi < 4; ++mi) {
    #pragma unroll
    for (int ni = 0; ni < 4; ++ni) {
      const int c = c0 + wn*64 + ni*16 + ci;
      float bb, sc;
      if (PROJ) {
        const float* bias = (c < D_) ? b0 : (c < 2*D_) ? b1 : b2;
        bb = bias[c & (D_-1)];
        sc = (c < D_) ? 0.03125f : 1.0f;   // q pre-scaled by 1/sqrt(D)
      } else { bb = b0 ? b0[c] : 0.0f; sc = scale; }
      #pragma unroll
      for (int j = 0; j < 4; ++j) {
        const int r = r0 + wm*64 + mi*16 + ri + j;
        const float v = (acc[mi][ni][j] + bb) * sc;
        if (OUT_BF16) ((bf16_t*)Cv + (size_t)z * sC)[(size_t)r * ldc + c] = (bf16_t)v;
        else          ((float*)Cv  + (size_t)z * sC)[(size_t)r * ldc + c] = v;
      }
    }
  }
}

__device__ __forceinline__ float blk_red_max(float v, float* red, int lane, int wid) {
  #pragma unroll
  for (int o = 32; o; o >>= 1) v = fmaxf(v, __shfl_down(v, o));
  __syncthreads();
  if (lane == 0) red[wid] = v;
  __syncthreads();
  return fmaxf(fmaxf(red[0], red[1]), fmaxf(red[2], red[3]));
}
__device__ __forceinline__ float blk_red_sum(float v, float* red, int lane, int wid) {
  #pragma unroll
  for (int o = 32; o; o >>= 1) v += __shfl_down(v, o);
  __syncthreads();
  if (lane == 0) red[wid] = v;
  __syncthreads();
  return red[0] + red[1] + red[2] + red[3];
}

// block (x=row r, y=batch); softmax over S[r][0..r], write bf16 P, zero-fill to 128-aligned end
__global__ __launch_bounds__(256)
void softmax_causal(const float* __restrict__ S, bf16_t* __restrict__ P) {
  const int r = blockIdx.x;
  const int n = r + 1;
  const int kend = min(((n + 127) >> 7) << 7, L_);
  const float* row = S + (size_t)blockIdx.y * L_ * L_ + (size_t)r * L_;
  bf16_t* prow = P + (size_t)blockIdx.y * L_ * L_ + (size_t)r * L_;
  const int tid = threadIdx.x, lane = tid & 63, wid = tid >> 6;
  __shared__ float red[4];

  float mx = -3.402823466e38f;
  #pragma unroll
  for (int i = 0; i < 8; ++i) {
    const int c = tid + i*256;
    if (c < n) mx = fmaxf(mx, row[c]);
  }
  mx = blk_red_max(mx, red, lane, wid);

  float e[8]; float sum = 0.f;
  #pragma unroll
  for (int i = 0; i < 8; ++i) {
    const int c = tid + i*256;
    const float v = (c < n) ? __expf(row[c] - mx) : 0.f;
    e[i] = v; sum += v;
  }
  sum = blk_red_sum(sum, red, lane, wid);
  const float inv = 1.0f / sum;
  #pragma unroll
  for (int i = 0; i < 8; ++i) {
    const int c = tid + i*256;
    if (c < kend) prow[c] = (bf16_t)(e[i] * inv);   // e==0 in [n,kend) -> zeros
  }
}

__global__ void cvt_f32_bf16(const float* __restrict__ in, bf16_t* __restrict__ out, int n4) {
  const int stride = gridDim.x * blockDim.x;
  for (int i = blockIdx.x * blockDim.x + threadIdx.x; i < n4; i += stride) {
    const float4 v = ((const float4*)in)[i];
    bf16x4 o = { (bf16_t)v.x, (bf16_t)v.y, (bf16_t)v.z, (bf16_t)v.w };
    ((bf16x4*)out)[i] = o;
  }
}

// oT[z][n][k] = w_z[k][n], fp32 -> bf16, 1024x1024 each; z concatenated -> [3072][1024]
__global__ void transpose_w3(const float* __restrict__ w0, const float* __restrict__ w1,
                             const float* __restrict__ w2, bf16_t* __restrict__ oT) {
  const float* w = blockIdx.z == 0 ? w0 : (blockIdx.z == 1 ? w1 : w2);
  bf16_t* o = oT + (size_t)blockIdx.z * D_ * D_;
  __shared__ float t[32][33];
  const int tx = threadIdx.x, ty = threadIdx.y;
  const int x  = blockIdx.x*32 + tx;
  const int y0 = blockIdx.y*32;
  #pragma unroll
  for (int j = 0; j < 4; ++j)
    t[ty + j*8][tx] = w[(size_t)(y0 + ty + j*8) * D_ + x];
  __syncthreads();
  const int x2 = y0 + tx;
  const int y2 = blockIdx.x*32;
  #pragma unroll
  for (int j = 0; j < 4; ++j)
    o[(size_t)(y2 + ty + j*8) * D_ + x2] = (bf16_t)t[tx][ty + j*8];
}

// out[C][R] = in[r][coff + c] for r<R, c<C; in has leading dim ld_in (bf16)
__global__ void transpose_bf16(const bf16_t* __restrict__ in, int ld_in, int coff,
                               bf16_t* __restrict__ out, int R, int C) {
  __shared__ bf16_t t[32][34];
  const int tx = threadIdx.x, ty = threadIdx.y;
  const int x  = blockIdx.x*32 + tx;
  const int y0 = blockIdx.y*32;
  #pragma unroll
  for (int j = 0; j < 4; ++j)
    t[ty + j*8][tx] = in[(size_t)(y0 + ty + j*8) * ld_in + coff + x];
  __syncthreads();
  const int x2 = y0 + tx;
  const int y2 = blockIdx.x*32;
  #pragma unroll
  for (int j = 0; j < 4; ++j)
    out[(size_t)(y2 + ty + j*8) * R + x2] = t[tx][ty + j*8];
}

extern "C" void kernel_launch(void* const* d_in, const int* in_sizes, int n_in,
                              void* d_out, int out_size, void* d_ws, size_t ws_size,
                              hipStream_t stream) {
  const float* x  = (const float*)d_in[0];
  // d_in[1] = causal mask, structurally known -> ignored
  const float* wq = (const float*)d_in[2];
  const float* bq = (const float*)d_in[3];
  const float* wk = (const float*)d_in[4];
  const float* bk = (const float*)d_in[5];
  const float* wv = (const float*)d_in[6];
  const float* bv = (const float*)d_in[7];
  float* out = (float*)d_out;

  // workspace layout (bf16 elems unless noted), ~150 MB total
  bf16_t* xb   = (bf16_t*)d_ws;                    // [8192][1024]    16 MB
  bf16_t* wT   = xb  + (size_t)M_ * D_;            // [3072][1024]     6 MB (W^T, q|k|v)
  bf16_t* qkv  = wT  + (size_t)N3_ * D_;           // [8192][3072]    48 MB (q pre-scaled)
  bf16_t* vbT  = qkv + (size_t)M_ * N3_;           // [1024][8192]    16 MB (V^T)
  float*  Sfull = (float*)(vbT + (size_t)M_ * D_); // [4][2048][2048] 64 MB f32
  bf16_t* Pfull = qkv;                             // [4][2048][2048] 32 MB (aliases dead qkv)

  cvt_f32_bf16<<<1024, 256, 0, stream>>>(x, xb, M_ * D_ / 4);
  transpose_w3<<<dim3(32,32,3), dim3(32,8), 0, stream>>>(wq, wk, wv, wT);

  // fused single projection GEMM: C[8192][3072] = xb @ wT^T, bias/scale per column
  gemm_abt<true,false,false,true><<<dim3(N3_/128, M_/128), 256, 0, stream>>>(
      xb, D_, 0, wT, D_, 0, qkv, N3_, 0, bq, bk, bv, 1.0f, D_);

  // V^T from qkv columns [2048,3072)
  transpose_bf16<<<dim3(D_/32, M_/32), dim3(32,8), 0, stream>>>(qkv, N3_, 2*D_, vbT, M_, D_);

  // QK^T for all batches (Q = cols [0,1024), K = cols [1024,2048))
  gemm_abt<false,true,false,false><<<dim3(L_/128, L_/128, B_), 256, 0, stream>>>(
      qkv, N3_, (long)L_*N3_, qkv + D_, N3_, (long)L_*N3_, Sfull, L_, (long)L_*L_,
      nullptr, nullptr, nullptr, 1.0f, D_);

  // softmax for all batches (writes Pfull over dead qkv)
  softmax_causal<<<dim3(L_, B_), 256, 0, stream>>>(Sfull, Pfull);

  // PV for all batches
  gemm_abt<false,false,true,false><<<dim3(D_/128, L_/128, B_), 256, 0, stream>>>(
      Pfull, L_, (long)L_*L_, vbT, M_, (long)L_, out, D_, (long)L_*D_,
      nullptr, nullptr, nullptr, 1.0f, L_);
}

// Round 4
// 214.163 us; speedup vs baseline: 1.9343x; 1.0886x over previous
//
#include <hip/hip_runtime.h>

typedef __bf16 bf16_t;
typedef __attribute__((ext_vector_type(8))) __bf16 bf16x8;
typedef __attribute__((ext_vector_type(4))) __bf16 bf16x4;
typedef __attribute__((ext_vector_type(4))) float f32x4;

#define B_  4
#define L_  2048
#define D_  1024
#define M_  (B_*L_)
#define N3_ (3*D_)

__device__ __forceinline__ void gload_lds16(const void* g, void* l) {
  __builtin_amdgcn_global_load_lds(
      (__attribute__((address_space(1))) void*)(g),
      (__attribute__((address_space(3))) void*)(l), 16, 0, 0);
}

// Stage one half-tile (128 rows x 64 cols bf16) into LDS via global_load_lds.
// LDS dest is linear; global source column is pre-swizzled (c16 ^= row&7) so that
// swizzled ds_reads see conflict-free banks (T2 via m173 pattern).
__device__ __forceinline__ void stage_half(const bf16_t* __restrict__ g, int ld, int grow0,
                                           int k0, bf16_t* lds_tile, int h, int tid) {
  const int lane = tid & 63;
  const int csrc = ((lane & 7) ^ (lane >> 3)) << 3;   // element offset within 64-col row
  const int rsub = tid >> 3;                           // 0..63
  bf16_t* l0 = lds_tile + (size_t)(h * 128 + ((tid >> 6) << 3)) * 64;
  const bf16_t* g0 = g + (size_t)(grow0 + h * 128 + rsub) * ld + (k0 + csrc);
  gload_lds16(g0, l0);
  gload_lds16(g0 + (size_t)64 * ld, l0 + 64 * 64);
}

// One phase: quadrant Q of tile j. Q=(mh,nh) with mh=Q&1, nh=Q>>1.
// ds-reads + 1 half-tile stage -> barrier -> lgkmcnt(0) -> setprio(1) 16 MFMA setprio(0)
// -> [Q==3: counted vmcnt] -> barrier.
#define PHASE(q)                                                                  \
  do {                                                                            \
    constexpr int Q = (q);                                                        \
    constexpr int MH = Q & 1, NH = Q >> 1;                                        \
    if constexpr (Q == 0 || Q == 1) {                                             \
      _Pragma("unroll")                                                           \
      for (int mi = 0; mi < 4; ++mi) {                                            \
        aF[MH][mi][0] = *(const bf16x8*)(Ab + abase + (MH * 4 + mi) * 2048 + co0);\
        aF[MH][mi][1] = *(const bf16x8*)(Ab + abase + (MH * 4 + mi) * 2048 + co1);\
      }                                                                           \
    }                                                                             \
    bf16x8 bF[2][2];                                                              \
    _Pragma("unroll")                                                             \
    for (int ni = 0; ni < 2; ++ni) {                                              \
      bF[ni][0] = *(const bf16x8*)(Bb + bbase + (NH * 2 + ni) * 4096 + co0);      \
      bF[ni][1] = *(const bf16x8*)(Bb + bbase + (NH * 2 + ni) * 4096 + co1);      \
    }                                                                             \
    if constexpr (Q == 0) { if (j + 1 < NT) stage_half(Bt, ldb, c0, k1, Bn, 0, tid); } \
    if constexpr (Q == 1) { if (j + 1 < NT) stage_half(A,  lda, r0, k1, An, 1, tid); } \
    if constexpr (Q == 2) { if (j + 1 < NT) stage_half(Bt, ldb, c0, k1, Bn, 1, tid); } \
    if constexpr (Q == 3) { if (j + 2 < NT) stage_half(A,  lda, r0, k1 + 64, Acur, 0, tid); } \
    asm volatile("s_barrier" ::: "memory");                                       \
    asm volatile("s_waitcnt lgkmcnt(0)" ::: "memory");                            \
    __builtin_amdgcn_sched_barrier(0);                                            \
    __builtin_amdgcn_s_setprio(1);                                                \
    _Pragma("unroll")                                                             \
    for (int mi = 0; mi < 4; ++mi)                                                \
      _Pragma("unroll")                                                           \
      for (int ni = 0; ni < 2; ++ni) {                                            \
        acc[MH * 4 + mi][NH * 2 + ni] = __builtin_amdgcn_mfma_f32_16x16x32_bf16(  \
            aF[MH][mi][0], bF[ni][0], acc[MH * 4 + mi][NH * 2 + ni], 0, 0, 0);    \
        acc[MH * 4 + mi][NH * 2 + ni] = __builtin_amdgcn_mfma_f32_16x16x32_bf16(  \
            aF[MH][mi][1], bF[ni][1], acc[MH * 4 + mi][NH * 2 + ni], 0, 0, 0);    \
      }                                                                           \
    __builtin_amdgcn_s_setprio(0);                                                \
    if constexpr (Q == 3) {                                                       \
      if (j < NT - 1) {                                                           \
        if (j >= NT - 2) asm volatile("s_waitcnt vmcnt(0)" ::: "memory");         \
        else             asm volatile("s_waitcnt vmcnt(2)" ::: "memory");         \
      }                                                                           \
    }                                                                             \
    asm volatile("s_barrier" ::: "memory");                                       \
  } while (0)

// C[M][N] = A[M][K] * Bt[N][K]^T (+bias)*scale. 256x256 tile, BK=64, 512 threads,
// 8-phase schedule (T2+T3+T4+T5). blockIdx.z = batch slab. XCD swizzle (T1).
template<bool OUT_BF16, bool CAUSAL, bool VARK, bool PROJ>
__global__ __launch_bounds__(512, 2)
void gemm8(const bf16_t* __restrict__ A, int lda, long sA,
           const bf16_t* __restrict__ Bt, int ldb, long sB,
           void* __restrict__ Cv, int ldc, long sC,
           const float* __restrict__ b0, const float* __restrict__ b1,
           const float* __restrict__ b2, float scale, int K)
{
  const int gx = gridDim.x;
  const int nwg = gx * gridDim.y;
  const int orig = blockIdx.y * gx + blockIdx.x;
  const int swz = (orig & 7) * (nwg >> 3) + (orig >> 3);   // bijective: nwg % 8 == 0
  const int bx = swz % gx, by = swz / gx;
  if (CAUSAL && bx > by) return;

  const int z = blockIdx.z;
  A  += (size_t)z * sA;
  Bt += (size_t)z * sB;

  const int r0 = by * 256, c0 = bx * 256;
  const int kend = VARK ? min(K, r0 + 256) : K;
  const int NT = kend >> 6;

  extern __shared__ __align__(16) bf16_t smem[];
  bf16_t* sAl = smem;              // [2][256*64] A dbuf
  bf16_t* sBl = smem + 32768;      // [2][256*64] B dbuf

  const int tid = threadIdx.x;
  const int wid = tid >> 6, lane = tid & 63;
  const int wm = wid >> 2, wn = wid & 3;              // 2 x 4 waves
  const int rl = lane & 15, cg = lane >> 4, x0 = lane & 7;
  const int co0 = ((cg ^ x0) << 3);                   // swizzled k-chunk, ks=0
  const int co1 = (((4 + cg) ^ x0) << 3);             // ks=1
  const int abase = (wm * 16 + rl) * 64;
  const int bbase = (wn * 16 + rl) * 64;

  f32x4 acc[8][4] = {};
  bf16x8 aF[2][4][2];

  // prologue: stage tile0 fully (A0,B0,A1,B1) + tile1.A0; allow newest half-tile in flight
  stage_half(A,  lda, r0, 0, sAl, 0, tid);
  stage_half(Bt, ldb, c0, 0, sBl, 0, tid);
  stage_half(A,  lda, r0, 0, sAl, 1, tid);
  stage_half(Bt, ldb, c0, 0, sBl, 1, tid);
  if (NT > 1) stage_half(A, lda, r0, 64, sAl + 16384, 0, tid);
  asm volatile("s_waitcnt vmcnt(2)" ::: "memory");
  asm volatile("s_barrier" ::: "memory");

  for (int j = 0; j < NT; ++j) {
    const bf16_t* Ab = sAl + (j & 1) * 16384;
    const bf16_t* Bb = sBl + (j & 1) * 16384;
    bf16_t* Acur = sAl + (j & 1) * 16384;              // q3 stages tile j+2 here (A-half0)
    bf16_t* An = sAl + ((j + 1) & 1) * 16384;
    bf16_t* Bn = sBl + ((j + 1) & 1) * 16384;
    const int k1 = (j + 1) << 6;
    PHASE(0); PHASE(1); PHASE(2); PHASE(3);
  }

  // epilogue
  const int ci = lane & 15, ri4 = cg * 4;
  #pragma unroll
  for (int mi = 0; mi < 8; ++mi) {
    #pragma unroll
    for (int ni = 0; ni < 4; ++ni) {
      const int c = c0 + ni * 64 + wn * 16 + ci;
      float bb, sc;
      if (PROJ) {
        const float* bias = (c < D_) ? b0 : (c < 2 * D_) ? b1 : b2;
        bb = bias[c & (D_ - 1)];
        sc = (c < D_) ? 0.03125f : 1.0f;   // q pre-scaled by 1/sqrt(D)
      } else { bb = b0 ? b0[c] : 0.0f; sc = scale; }
      const int r = r0 + mi * 32 + wm * 16 + ri4;
      #pragma unroll
      for (int jj = 0; jj < 4; ++jj) {
        const float v = (acc[mi][ni][jj] + bb) * sc;
        if (OUT_BF16) ((bf16_t*)Cv + (size_t)z * sC)[(size_t)(r + jj) * ldc + c] = (bf16_t)v;
        else          ((float*)Cv  + (size_t)z * sC)[(size_t)(r + jj) * ldc + c] = v;
      }
    }
  }
}

__device__ __forceinline__ float blk_red_max(float v, float* red, int lane, int wid) {
  #pragma unroll
  for (int o = 32; o; o >>= 1) v = fmaxf(v, __shfl_down(v, o));
  __syncthreads();
  if (lane == 0) red[wid] = v;
  __syncthreads();
  return fmaxf(fmaxf(red[0], red[1]), fmaxf(red[2], red[3]));
}
__device__ __forceinline__ float blk_red_sum(float v, float* red, int lane, int wid) {
  #pragma unroll
  for (int o = 32; o; o >>= 1) v += __shfl_down(v, o);
  __syncthreads();
  if (lane == 0) red[wid] = v;
  __syncthreads();
  return red[0] + red[1] + red[2] + red[3];
}

// block (x=row r, y=batch); softmax over S[r][0..r], write bf16 P, zero-fill to
// 256-aligned end (PV tiles are 256 wide in K).
__global__ __launch_bounds__(256)
void softmax_causal(const float* __restrict__ S, bf16_t* __restrict__ P) {
  const int r = blockIdx.x;
  const int n = r + 1;
  const int kend = min(((n + 255) >> 8) << 8, L_);
  const float* row = S + (size_t)blockIdx.y * L_ * L_ + (size_t)r * L_;
  bf16_t* prow = P + (size_t)blockIdx.y * L_ * L_ + (size_t)r * L_;
  const int tid = threadIdx.x, lane = tid & 63, wid = tid >> 6;
  __shared__ float red[4];

  float mx = -3.402823466e38f;
  #pragma unroll
  for (int i = 0; i < 8; ++i) {
    const int c = tid + i * 256;
    if (c < n) mx = fmaxf(mx, row[c]);
  }
  mx = blk_red_max(mx, red, lane, wid);

  float e[8]; float sum = 0.f;
  #pragma unroll
  for (int i = 0; i < 8; ++i) {
    const int c = tid + i * 256;
    const float v = (c < n) ? __expf(row[c] - mx) : 0.f;
    e[i] = v; sum += v;
  }
  sum = blk_red_sum(sum, red, lane, wid);
  const float inv = 1.0f / sum;
  #pragma unroll
  for (int i = 0; i < 8; ++i) {
    const int c = tid + i * 256;
    if (c < kend) prow[c] = (bf16_t)(e[i] * inv);   // e==0 in [n,kend) -> zeros
  }
}

__global__ void cvt_f32_bf16(const float* __restrict__ in, bf16_t* __restrict__ out, int n4) {
  const int stride = gridDim.x * blockDim.x;
  for (int i = blockIdx.x * blockDim.x + threadIdx.x; i < n4; i += stride) {
    const float4 v = ((const float4*)in)[i];
    bf16x4 o = { (bf16_t)v.x, (bf16_t)v.y, (bf16_t)v.z, (bf16_t)v.w };
    ((bf16x4*)out)[i] = o;
  }
}

// oT[z][n][k] = w_z[k][n], fp32 -> bf16, 1024x1024 each; z concatenated -> [3072][1024]
__global__ void transpose_w3(const float* __restrict__ w0, const float* __restrict__ w1,
                             const float* __restrict__ w2, bf16_t* __restrict__ oT) {
  const float* w = blockIdx.z == 0 ? w0 : (blockIdx.z == 1 ? w1 : w2);
  bf16_t* o = oT + (size_t)blockIdx.z * D_ * D_;
  __shared__ float t[32][33];
  const int tx = threadIdx.x, ty = threadIdx.y;
  const int x  = blockIdx.x * 32 + tx;
  const int y0 = blockIdx.y * 32;
  #pragma unroll
  for (int j = 0; j < 4; ++j)
    t[ty + j * 8][tx] = w[(size_t)(y0 + ty + j * 8) * D_ + x];
  __syncthreads();
  const int x2 = y0 + tx;
  const int y2 = blockIdx.x * 32;
  #pragma unroll
  for (int j = 0; j < 4; ++j)
    o[(size_t)(y2 + ty + j * 8) * D_ + x2] = (bf16_t)t[tx][ty + j * 8];
}

// out[C][R] = in[r][coff + c] for r<R, c<C; in has leading dim ld_in (bf16)
__global__ void transpose_bf16(const bf16_t* __restrict__ in, int ld_in, int coff,
                               bf16_t* __restrict__ out, int R, int C) {
  __shared__ bf16_t t[32][34];
  const int tx = threadIdx.x, ty = threadIdx.y;
  const int x  = blockIdx.x * 32 + tx;
  const int y0 = blockIdx.y * 32;
  #pragma unroll
  for (int j = 0; j < 4; ++j)
    t[ty + j * 8][tx] = in[(size_t)(y0 + ty + j * 8) * ld_in + coff + x];
  __syncthreads();
  const int x2 = y0 + tx;
  const int y2 = blockIdx.x * 32;
  #pragma unroll
  for (int j = 0; j < 4; ++j)
    out[(size_t)(y2 + ty + j * 8) * R + x2] = t[tx][ty + j * 8];
}

extern "C" void kernel_launch(void* const* d_in, const int* in_sizes, int n_in,
                              void* d_out, int out_size, void* d_ws, size_t ws_size,
                              hipStream_t stream) {
  const float* x  = (const float*)d_in[0];
  // d_in[1] = causal mask, structurally known -> ignored
  const float* wq = (const float*)d_in[2];
  const float* bq = (const float*)d_in[3];
  const float* wk = (const float*)d_in[4];
  const float* bk = (const float*)d_in[5];
  const float* wv = (const float*)d_in[6];
  const float* bv = (const float*)d_in[7];
  float* out = (float*)d_out;

  // workspace layout (bf16 elems unless noted), ~150 MB total
  bf16_t* xb   = (bf16_t*)d_ws;                    // [8192][1024]    16 MB
  bf16_t* wT   = xb  + (size_t)M_ * D_;            // [3072][1024]     6 MB (W^T, q|k|v)
  bf16_t* qkv  = wT  + (size_t)N3_ * D_;           // [8192][3072]    48 MB (q pre-scaled)
  bf16_t* vbT  = qkv + (size_t)M_ * N3_;           // [1024][8192]    16 MB (V^T)
  float*  Sfull = (float*)(vbT + (size_t)M_ * D_); // [4][2048][2048] 64 MB f32
  bf16_t* Pfull = qkv;                             // [4][2048][2048] 32 MB (aliases dead qkv)

  const size_t SMEM = 131072;   // 128 KiB dbuf

  cvt_f32_bf16<<<1024, 256, 0, stream>>>(x, xb, M_ * D_ / 4);
  transpose_w3<<<dim3(32, 32, 3), dim3(32, 8), 0, stream>>>(wq, wk, wv, wT);

  // fused projection GEMM: C[8192][3072] = xb @ wT^T, bias/scale per column
  gemm8<true, false, false, true><<<dim3(N3_ / 256, M_ / 256), 512, SMEM, stream>>>(
      xb, D_, 0, wT, D_, 0, qkv, N3_, 0, bq, bk, bv, 1.0f, D_);

  // V^T from qkv columns [2048,3072)
  transpose_bf16<<<dim3(D_ / 32, M_ / 32), dim3(32, 8), 0, stream>>>(qkv, N3_, 2 * D_, vbT, M_, D_);

  // QK^T for all batches (Q = cols [0,1024), K = cols [1024,2048))
  gemm8<false, true, false, false><<<dim3(L_ / 256, L_ / 256, B_), 512, SMEM, stream>>>(
      qkv, N3_, (long)L_ * N3_, qkv + D_, N3_, (long)L_ * N3_, Sfull, L_, (long)L_ * L_,
      nullptr, nullptr, nullptr, 1.0f, D_);

  // softmax for all batches (writes Pfull over dead qkv)
  softmax_causal<<<dim3(L_, B_), 256, 0, stream>>>(Sfull, Pfull);

  // PV for all batches
  gemm8<false, false, true, false><<<dim3(D_ / 256, L_ / 256, B_), 512, SMEM, stream>>>(
      Pfull, L_, (long)L_ * L_, vbT, M_, (long)L_, out, D_, (long)L_ * D_,
      nullptr, nullptr, nullptr, 1.0f, L_);
}